// Round 4
// baseline (2171.668 us; speedup 1.0000x reference)
//
#include <hip/hip_runtime.h>
#include <hip/hip_bf16.h>
#include <math.h>

#define S_LEN 2048
#define HID 2560
#define NH 8
#define NKV 4
#define HD 256
#define WINDOW 1024

// C[M,N] = A[M,K] @ B[K,N], row-major fp32. 64x64x16 tiles, 256 thr, 4x4/thr.
__global__ __launch_bounds__(256)
void gemm_f32(const float* __restrict__ A, const float* __restrict__ Bm,
              float* __restrict__ C, int M, int N, int K) {
  __shared__ float As[16][68];  // [k][m]
  __shared__ float Bs[16][68];  // [k][n]
  const int tid = threadIdx.x;
  const int tx = tid & 15;
  const int ty = tid >> 4;
  const int rowBase = blockIdx.y * 64;
  const int colBase = blockIdx.x * 64;
  float acc[4][4] = {};
  for (int k0 = 0; k0 < K; k0 += 16) {
#pragma unroll
    for (int i = 0; i < 4; i++) {
      int idx = tid + i * 256;
      int r = idx >> 4, c = idx & 15;  // r = row-in-tile, c = k-in-tile
      As[c][r] = A[(size_t)(rowBase + r) * K + (k0 + c)];
    }
#pragma unroll
    for (int i = 0; i < 4; i++) {
      int idx = tid + i * 256;
      int r = idx >> 6, c = idx & 63;  // r = k-in-tile, c = col-in-tile
      Bs[r][c] = Bm[(size_t)(k0 + r) * N + (colBase + c)];
    }
    __syncthreads();
#pragma unroll
    for (int kk = 0; kk < 16; kk++) {
      float a[4], b[4];
#pragma unroll
      for (int i = 0; i < 4; i++) a[i] = As[kk][ty * 4 + i];
#pragma unroll
      for (int j = 0; j < 4; j++) b[j] = Bs[kk][tx * 4 + j];
#pragma unroll
      for (int i = 0; i < 4; i++)
#pragma unroll
        for (int j = 0; j < 4; j++) acc[i][j] += a[i] * b[j];
    }
    __syncthreads();
  }
#pragma unroll
  for (int i = 0; i < 4; i++)
#pragma unroll
    for (int j = 0; j < 4; j++)
      C[(size_t)(rowBase + ty * 4 + i) * N + (colBase + tx * 4 + j)] =
          acc[i][j];
}

// One block per (seq, head) row of HD=256. RMSNorm (+opt weight) then opt RoPE.
// Writes [h][d][s] layout if transpose_out (for K).
__global__ __launch_bounds__(256)
void norm_rope_kernel(const float* __restrict__ in, float* __restrict__ out,
                      const float* __restrict__ w, const float* __restrict__ cosb,
                      const float* __restrict__ sinb, int H, int do_rope,
                      int transpose_out) {
  const int sq = blockIdx.x / H;
  const int h = blockIdx.x % H;
  const int d = threadIdx.x;
  float x = in[((size_t)sq * H + h) * HD + d];
  float v = x * x;
#pragma unroll
  for (int off = 32; off; off >>= 1) v += __shfl_down(v, off);
  __shared__ float red[4];
  __shared__ float sscale;
  if ((d & 63) == 0) red[d >> 6] = v;
  __syncthreads();
  if (d == 0)
    sscale = rsqrtf((red[0] + red[1] + red[2] + red[3]) * (1.0f / HD) + 1e-6f);
  __syncthreads();
  float n = x * sscale;
  if (w) n *= w[d];
  if (do_rope) {  // block-uniform branch
    __shared__ float nb[HD];
    nb[d] = n;
    __syncthreads();
    float other = (d < HD / 2) ? -nb[d + HD / 2] : nb[d - HD / 2];
    n = n * cosb[(size_t)sq * HD + d] + other * sinb[(size_t)sq * HD + d];
  }
  if (transpose_out)
    out[((size_t)h * HD + d) * S_LEN + sq] = n;
  else
    out[((size_t)sq * H + h) * HD + d] = n;
}

// One block (256 thr) per (seq, q-head). Scores via kT[kvh][d][s] (coalesced
// over keys), softmax in LDS, PV coalesced over d.
// ctx may alias qn: each block reads only its own q row (into LDS, before any
// write) and writes only its own ctx row at the end.
__global__ __launch_bounds__(256)
void attn_kernel(const float* __restrict__ qn, const float* __restrict__ kT,
                 const float* __restrict__ vn, float* __restrict__ ctx) {
  const int sq = blockIdx.x / NH;
  const int h = blockIdx.x % NH;
  const int kvh = h / (NH / NKV);
  const int t = threadIdx.x;
  __shared__ float qv[HD];
  __shared__ float p[WINDOW];
  __shared__ float red[4];
  __shared__ float bval;
  qv[t] = qn[((size_t)sq * NH + h) * HD + t];
  const int k0 = (sq >= WINDOW) ? sq - (WINDOW - 1) : 0;
  const int cnt = sq - k0 + 1;          // 1..1024
  const int nchunk = (cnt + 255) >> 8;  // 1..4, block-uniform
  __syncthreads();
  float scv[4] = {-INFINITY, -INFINITY, -INFINITY, -INFINITY};
  const float* kbase = kT + (size_t)kvh * HD * S_LEN + k0;
  for (int i = 0; i < nchunk; i++) {
    const int j = t + (i << 8);
    const float* kp = kbase + j;
    float acc = 0.f;
#pragma unroll 8
    for (int d2 = 0; d2 < HD; d2++) acc += qv[d2] * kp[(size_t)d2 * S_LEN];
    scv[i] = (j < cnt) ? acc : -INFINITY;
  }
  // block max
  float m = fmaxf(fmaxf(scv[0], scv[1]), fmaxf(scv[2], scv[3]));
#pragma unroll
  for (int off = 32; off; off >>= 1) m = fmaxf(m, __shfl_down(m, off));
  if ((t & 63) == 0) red[t >> 6] = m;
  __syncthreads();
  if (t == 0) bval = fmaxf(fmaxf(red[0], red[1]), fmaxf(red[2], red[3]));
  __syncthreads();
  const float mx = bval;
  // exp + block sum
  float lsum = 0.f;
#pragma unroll
  for (int i = 0; i < 4; i++) {
    float e = expf(scv[i] - mx);  // exp(-inf)=0 for masked slots
    lsum += e;
    if (i < nchunk) p[t + (i << 8)] = e;
  }
#pragma unroll
  for (int off = 32; off; off >>= 1) lsum += __shfl_down(lsum, off);
  if ((t & 63) == 0) red[t >> 6] = lsum;
  __syncthreads();
  if (t == 0) bval = red[0] + red[1] + red[2] + red[3];
  __syncthreads();
  const float inv = 1.0f / bval;
  // PV: thread t owns dim d=t
  float o = 0.f;
  const float* vp = vn + ((size_t)k0 * NKV + kvh) * HD + t;
  for (int j = 0; j < cnt; j++) o += p[j] * vp[(size_t)j * NKV * HD];
  ctx[((size_t)sq * NH + h) * HD + t] = o * inv;
}

extern "C" void kernel_launch(void* const* d_in, const int* in_sizes, int n_in,
                              void* d_out, int out_size, void* d_ws, size_t ws_size,
                              hipStream_t stream) {
  const float* hs   = (const float*)d_in[0];
  const float* cosb = (const float*)d_in[1];
  const float* sinb = (const float*)d_in[2];
  const float* wq   = (const float*)d_in[3];
  const float* wk   = (const float*)d_in[4];
  const float* wv   = (const float*)d_in[5];
  const float* wo   = (const float*)d_in[6];
  const float* qw   = (const float*)d_in[7];
  const float* kw   = (const float*)d_in[8];

  // fp32 workspace, 32 MB total, aliased by lifetime:
  //   qc : q rows, later overwritten per-row by attn as ctx  (16 MB)
  //   kT : transposed normed K [kvh][d][s]                    (8 MB)
  //   kv : k GEMM output (kraw), later v GEMM output + norm   (8 MB)
  float* qc = (float*)((char*)d_ws + 256);
  float* kT = qc + (size_t)S_LEN * NH * HD;   // 4M floats after qc
  float* kv = kT + (size_t)NKV * HD * S_LEN;  // 2M floats after kT

  dim3 blk(256);
  const dim3 gq((NH * HD) / 64, S_LEN / 64);
  const dim3 gkv((NKV * HD) / 64, S_LEN / 64);
  const dim3 go(HID / 64, S_LEN / 64);

  // q projection
  gemm_f32<<<gq, blk, 0, stream>>>(hs, wq, qc, S_LEN, NH * HD, HID);
  // k projection -> kv (kraw), then norm+rope+transpose -> kT
  gemm_f32<<<gkv, blk, 0, stream>>>(hs, wk, kv, S_LEN, NKV * HD, HID);
  norm_rope_kernel<<<S_LEN * NKV, blk, 0, stream>>>(kv, kT, kw, cosb, sinb,
                                                    NKV, 1, 1);
  // v projection -> kv (kraw dead), then norm in place
  gemm_f32<<<gkv, blk, 0, stream>>>(hs, wv, kv, S_LEN, NKV * HD, HID);
  norm_rope_kernel<<<S_LEN * NKV, blk, 0, stream>>>(kv, kv, nullptr, nullptr,
                                                    nullptr, NKV, 0, 0);
  // q norm+rope in place
  norm_rope_kernel<<<S_LEN * NH, blk, 0, stream>>>(qc, qc, qw, cosb, sinb,
                                                   NH, 1, 0);
  // attention (ctx aliases qc row-wise, safe)
  attn_kernel<<<S_LEN * NH, blk, 0, stream>>>(qc, kT, kv, qc);
  // output projection
  gemm_f32<<<go, blk, 0, stream>>>(qc, wo, (float*)d_out, S_LEN, HID, NH * HD);
}

// Round 5
// 1668.923 us; speedup vs baseline: 1.3012x; 1.3012x over previous
//
#include <hip/hip_runtime.h>
#include <hip/hip_bf16.h>
#include <math.h>

#define S_LEN 2048
#define HID 2560
#define NH 8
#define NKV 4
#define HD 256
#define WINDOW 1024

typedef short short8 __attribute__((ext_vector_type(8)));
typedef short short4_t __attribute__((ext_vector_type(4)));
typedef float f32x4 __attribute__((ext_vector_type(4)));
typedef float float4_t __attribute__((ext_vector_type(4)));

// round-to-nearest-even fp32 -> bf16 bits
__device__ __forceinline__ short bf16_rne(float x) {
  unsigned u = __float_as_uint(x);
  return (short)((u + 0x7FFFu + ((u >> 16) & 1u)) >> 16);
}
// split x = hi + lo (both bf16); hi*hi + hi*lo + lo*hi ~ fp32-accurate product
__device__ __forceinline__ void split2(float x, short &h, short &l) {
  unsigned u = __float_as_uint(x);
  unsigned hb = (u + 0x7FFFu + ((u >> 16) & 1u)) & 0xFFFF0000u;
  h = (short)(hb >> 16);
  float r = x - __uint_as_float(hb);
  l = bf16_rne(r);
}

// C[M,N] = A[M,K] @ B[K,N], fp32 in/out, split-bf16 MFMA (3-product) inside.
// 128x128 tile, BK=32, 256 threads (4 waves), each wave 64x64 via 4x4 grid of
// 16x16x32 MFMAs. A staged [m][k] (k-contig); B transposed on stage to [n][k].
__global__ __launch_bounds__(256)
void gemm_mfma(const float* __restrict__ A, const float* __restrict__ B,
               float* __restrict__ C, int M, int N, int K) {
  __shared__ short Ah[128][32], Al[128][32];
  __shared__ short Bh[128][32], Bl[128][32];
  const int tid = threadIdx.x;
  const int wave = tid >> 6, lane = tid & 63;
  const int wm = (wave >> 1) * 64, wn = (wave & 1) * 64;
  const int m_in = lane & 15, kgrp = lane >> 4;  // C row group = kgrp*4+reg
  const int m0 = blockIdx.y * 128, n0 = blockIdx.x * 128;
  const int bn = tid & 127;         // B staging: n within tile
  const int bk0 = (tid >> 7) * 16;  // B staging: k half (0 or 16)

  f32x4 acc[4][4];
#pragma unroll
  for (int i = 0; i < 4; i++)
#pragma unroll
    for (int j = 0; j < 4; j++) acc[i][j] = (f32x4){0.f, 0.f, 0.f, 0.f};

  for (int k0 = 0; k0 < K; k0 += 32) {
    // ---- stage A: 128x32 fp32, coalesced float4, decompose to hi/lo ----
#pragma unroll
    for (int i = 0; i < 4; i++) {
      int f = tid + i * 256;           // float4 index 0..1023
      int m = f >> 3, c4 = (f & 7) << 2;
      float4_t av = *reinterpret_cast<const float4_t*>(
          &A[(size_t)(m0 + m) * K + (k0 + c4)]);
      short4_t hv, lv;
#pragma unroll
      for (int e = 0; e < 4; e++) {
        short h, l;
        split2(av[e], h, l);
        hv[e] = h; lv[e] = l;
      }
      *reinterpret_cast<short4_t*>(&Ah[m][c4]) = hv;
      *reinterpret_cast<short4_t*>(&Al[m][c4]) = lv;
    }
    // ---- stage B: 32x128 fp32, 16 n-coalesced strided loads, store [n][k] ----
    {
      const float* bp = &B[(size_t)(k0 + bk0) * N + (n0 + bn)];
      float vals[16];
#pragma unroll
      for (int kk = 0; kk < 16; kk++) vals[kk] = bp[(size_t)kk * N];
#pragma unroll
      for (int c = 0; c < 4; c++) {
        short4_t hv, lv;
#pragma unroll
        for (int e = 0; e < 4; e++) {
          short h, l;
          split2(vals[c * 4 + e], h, l);
          hv[e] = h; lv[e] = l;
        }
        *reinterpret_cast<short4_t*>(&Bh[bn][bk0 + c * 4]) = hv;
        *reinterpret_cast<short4_t*>(&Bl[bn][bk0 + c * 4]) = lv;
      }
    }
    __syncthreads();
    // ---- fragments + MFMA ----
    short8 ah[4], al[4], bh[4], bl[4];
#pragma unroll
    for (int i = 0; i < 4; i++) {
      ah[i] = *reinterpret_cast<const short8*>(&Ah[wm + i * 16 + m_in][kgrp * 8]);
      al[i] = *reinterpret_cast<const short8*>(&Al[wm + i * 16 + m_in][kgrp * 8]);
    }
#pragma unroll
    for (int j = 0; j < 4; j++) {
      bh[j] = *reinterpret_cast<const short8*>(&Bh[wn + j * 16 + m_in][kgrp * 8]);
      bl[j] = *reinterpret_cast<const short8*>(&Bl[wn + j * 16 + m_in][kgrp * 8]);
    }
#pragma unroll
    for (int i = 0; i < 4; i++)
#pragma unroll
      for (int j = 0; j < 4; j++) {
        acc[i][j] = __builtin_amdgcn_mfma_f32_16x16x32_bf16(ah[i], bh[j], acc[i][j], 0, 0, 0);
        acc[i][j] = __builtin_amdgcn_mfma_f32_16x16x32_bf16(ah[i], bl[j], acc[i][j], 0, 0, 0);
        acc[i][j] = __builtin_amdgcn_mfma_f32_16x16x32_bf16(al[i], bh[j], acc[i][j], 0, 0, 0);
      }
    __syncthreads();
  }
  // ---- epilogue: C/D layout col=lane&15, row=(lane>>4)*4+reg (m89) ----
#pragma unroll
  for (int i = 0; i < 4; i++)
#pragma unroll
    for (int j = 0; j < 4; j++)
#pragma unroll
      for (int r = 0; r < 4; r++) {
        int row = m0 + wm + i * 16 + kgrp * 4 + r;
        int col = n0 + wn + j * 16 + m_in;
        C[(size_t)row * N + col] = acc[i][j][r];
      }
}

// One block per (seq, head) row of HD=256. RMSNorm (+opt weight) then opt RoPE.
// Writes [h][d][s] layout if transpose_out (for K).
__global__ __launch_bounds__(256)
void norm_rope_kernel(const float* __restrict__ in, float* __restrict__ out,
                      const float* __restrict__ w, const float* __restrict__ cosb,
                      const float* __restrict__ sinb, int H, int do_rope,
                      int transpose_out) {
  const int sq = blockIdx.x / H;
  const int h = blockIdx.x % H;
  const int d = threadIdx.x;
  float x = in[((size_t)sq * H + h) * HD + d];
  float v = x * x;
#pragma unroll
  for (int off = 32; off; off >>= 1) v += __shfl_down(v, off);
  __shared__ float red[4];
  __shared__ float sscale;
  if ((d & 63) == 0) red[d >> 6] = v;
  __syncthreads();
  if (d == 0)
    sscale = rsqrtf((red[0] + red[1] + red[2] + red[3]) * (1.0f / HD) + 1e-6f);
  __syncthreads();
  float n = x * sscale;
  if (w) n *= w[d];
  if (do_rope) {  // block-uniform branch
    __shared__ float nb[HD];
    nb[d] = n;
    __syncthreads();
    float other = (d < HD / 2) ? -nb[d + HD / 2] : nb[d - HD / 2];
    n = n * cosb[(size_t)sq * HD + d] + other * sinb[(size_t)sq * HD + d];
  }
  if (transpose_out)
    out[((size_t)h * HD + d) * S_LEN + sq] = n;
  else
    out[((size_t)sq * H + h) * HD + d] = n;
}

// One block (256 thr) per (seq, q-head). Scores via kT[kvh][d][s] (coalesced
// over keys), softmax in LDS, PV coalesced over d. ctx may alias qn.
__global__ __launch_bounds__(256)
void attn_kernel(const float* __restrict__ qn, const float* __restrict__ kT,
                 const float* __restrict__ vn, float* __restrict__ ctx) {
  const int sq = blockIdx.x / NH;
  const int h = blockIdx.x % NH;
  const int kvh = h / (NH / NKV);
  const int t = threadIdx.x;
  __shared__ float qv[HD];
  __shared__ float p[WINDOW];
  __shared__ float red[4];
  __shared__ float bval;
  qv[t] = qn[((size_t)sq * NH + h) * HD + t];
  const int k0 = (sq >= WINDOW) ? sq - (WINDOW - 1) : 0;
  const int cnt = sq - k0 + 1;          // 1..1024
  const int nchunk = (cnt + 255) >> 8;  // 1..4, block-uniform
  __syncthreads();
  float scv[4] = {-INFINITY, -INFINITY, -INFINITY, -INFINITY};
  const float* kbase = kT + (size_t)kvh * HD * S_LEN + k0;
  for (int i = 0; i < nchunk; i++) {
    const int j = t + (i << 8);
    const float* kp = kbase + j;
    float acc = 0.f;
#pragma unroll 8
    for (int d2 = 0; d2 < HD; d2++) acc += qv[d2] * kp[(size_t)d2 * S_LEN];
    scv[i] = (j < cnt) ? acc : -INFINITY;
  }
  float m = fmaxf(fmaxf(scv[0], scv[1]), fmaxf(scv[2], scv[3]));
#pragma unroll
  for (int off = 32; off; off >>= 1) m = fmaxf(m, __shfl_down(m, off));
  if ((t & 63) == 0) red[t >> 6] = m;
  __syncthreads();
  if (t == 0) bval = fmaxf(fmaxf(red[0], red[1]), fmaxf(red[2], red[3]));
  __syncthreads();
  const float mx = bval;
  float lsum = 0.f;
#pragma unroll
  for (int i = 0; i < 4; i++) {
    float e = expf(scv[i] - mx);  // exp(-inf)=0 for masked slots
    lsum += e;
    if (i < nchunk) p[t + (i << 8)] = e;
  }
#pragma unroll
  for (int off = 32; off; off >>= 1) lsum += __shfl_down(lsum, off);
  if ((t & 63) == 0) red[t >> 6] = lsum;
  __syncthreads();
  if (t == 0) bval = red[0] + red[1] + red[2] + red[3];
  __syncthreads();
  const float inv = 1.0f / bval;
  float o = 0.f;
  const float* vp = vn + ((size_t)k0 * NKV + kvh) * HD + t;
  for (int j = 0; j < cnt; j++) o += p[j] * vp[(size_t)j * NKV * HD];
  ctx[((size_t)sq * NH + h) * HD + t] = o * inv;
}

extern "C" void kernel_launch(void* const* d_in, const int* in_sizes, int n_in,
                              void* d_out, int out_size, void* d_ws, size_t ws_size,
                              hipStream_t stream) {
  const float* hs   = (const float*)d_in[0];
  const float* cosb = (const float*)d_in[1];
  const float* sinb = (const float*)d_in[2];
  const float* wq   = (const float*)d_in[3];
  const float* wk   = (const float*)d_in[4];
  const float* wv   = (const float*)d_in[5];
  const float* wo   = (const float*)d_in[6];
  const float* qw   = (const float*)d_in[7];
  const float* kw   = (const float*)d_in[8];

  // fp32 workspace, 32 MB total (proven), aliased by lifetime:
  float* qc = (float*)((char*)d_ws + 256);    // S*NH*HD (q, then ctx)
  float* kT = qc + (size_t)S_LEN * NH * HD;   // NKV*HD*S
  float* kv = kT + (size_t)NKV * HD * S_LEN;  // S*NKV*HD (kraw, then v)

  dim3 blk(256);
  // q projection (M=2048, N=2048, K=2560)
  gemm_mfma<<<dim3((NH * HD) / 128, S_LEN / 128), blk, 0, stream>>>(
      hs, wq, qc, S_LEN, NH * HD, HID);
  // k projection -> kv (kraw), then norm+rope+transpose -> kT
  gemm_mfma<<<dim3((NKV * HD) / 128, S_LEN / 128), blk, 0, stream>>>(
      hs, wk, kv, S_LEN, NKV * HD, HID);
  norm_rope_kernel<<<S_LEN * NKV, blk, 0, stream>>>(kv, kT, kw, cosb, sinb,
                                                    NKV, 1, 1);
  // v projection -> kv (kraw dead), then norm in place
  gemm_mfma<<<dim3((NKV * HD) / 128, S_LEN / 128), blk, 0, stream>>>(
      hs, wv, kv, S_LEN, NKV * HD, HID);
  norm_rope_kernel<<<S_LEN * NKV, blk, 0, stream>>>(kv, kv, nullptr, nullptr,
                                                    nullptr, NKV, 0, 0);
  // q norm+rope in place
  norm_rope_kernel<<<S_LEN * NH, blk, 0, stream>>>(qc, qc, qw, cosb, sinb,
                                                   NH, 1, 0);
  // attention (ctx aliases qc row-wise, safe)
  attn_kernel<<<S_LEN * NH, blk, 0, stream>>>(qc, kT, kv, qc);
  // output projection (M=2048, N=2560, K=2048)
  gemm_mfma<<<dim3(HID / 128, S_LEN / 128), blk, 0, stream>>>(
      qc, wo, (float*)d_out, S_LEN, HID, NH * HD);
}

// Round 6
// 972.102 us; speedup vs baseline: 2.2340x; 1.7168x over previous
//
#include <hip/hip_runtime.h>
#include <hip/hip_bf16.h>
#include <math.h>

#define S_LEN 2048
#define HID 2560
#define NH 8
#define NKV 4
#define HD 256
#define WINDOW 1024

typedef short short8 __attribute__((ext_vector_type(8)));
typedef short short4_t __attribute__((ext_vector_type(4)));
typedef float f32x4 __attribute__((ext_vector_type(4)));
typedef float float4_t __attribute__((ext_vector_type(4)));

// round-to-nearest-even fp32 -> bf16 bits
__device__ __forceinline__ short bf16_rne(float x) {
  unsigned u = __float_as_uint(x);
  return (short)((u + 0x7FFFu + ((u >> 16) & 1u)) >> 16);
}
// split x = hi + lo (both bf16); hi*hi + hi*lo + lo*hi ~ fp32-accurate product
__device__ __forceinline__ void split2(float x, short &h, short &l) {
  unsigned u = __float_as_uint(x);
  unsigned hb = (u + 0x7FFFu + ((u >> 16) & 1u)) & 0xFFFF0000u;
  h = (short)(hb >> 16);
  float r = x - __uint_as_float(hb);
  l = bf16_rne(r);
}

// ---------------- GEMM (unchanged from round 5, proven) ----------------
__global__ __launch_bounds__(256)
void gemm_mfma(const float* __restrict__ A, const float* __restrict__ B,
               float* __restrict__ C, int M, int N, int K) {
  __shared__ short Ah[128][32], Al[128][32];
  __shared__ short Bh[128][32], Bl[128][32];
  const int tid = threadIdx.x;
  const int wave = tid >> 6, lane = tid & 63;
  const int wm = (wave >> 1) * 64, wn = (wave & 1) * 64;
  const int m_in = lane & 15, kgrp = lane >> 4;
  const int m0 = blockIdx.y * 128, n0 = blockIdx.x * 128;
  const int bn = tid & 127;
  const int bk0 = (tid >> 7) * 16;

  f32x4 acc[4][4];
#pragma unroll
  for (int i = 0; i < 4; i++)
#pragma unroll
    for (int j = 0; j < 4; j++) acc[i][j] = (f32x4){0.f, 0.f, 0.f, 0.f};

  for (int k0 = 0; k0 < K; k0 += 32) {
#pragma unroll
    for (int i = 0; i < 4; i++) {
      int f = tid + i * 256;
      int m = f >> 3, c4 = (f & 7) << 2;
      float4_t av = *reinterpret_cast<const float4_t*>(
          &A[(size_t)(m0 + m) * K + (k0 + c4)]);
      short4_t hv, lv;
#pragma unroll
      for (int e = 0; e < 4; e++) {
        short h, l;
        split2(av[e], h, l);
        hv[e] = h; lv[e] = l;
      }
      *reinterpret_cast<short4_t*>(&Ah[m][c4]) = hv;
      *reinterpret_cast<short4_t*>(&Al[m][c4]) = lv;
    }
    {
      const float* bp = &B[(size_t)(k0 + bk0) * N + (n0 + bn)];
      float vals[16];
#pragma unroll
      for (int kk = 0; kk < 16; kk++) vals[kk] = bp[(size_t)kk * N];
#pragma unroll
      for (int c = 0; c < 4; c++) {
        short4_t hv, lv;
#pragma unroll
        for (int e = 0; e < 4; e++) {
          short h, l;
          split2(vals[c * 4 + e], h, l);
          hv[e] = h; lv[e] = l;
        }
        *reinterpret_cast<short4_t*>(&Bh[bn][bk0 + c * 4]) = hv;
        *reinterpret_cast<short4_t*>(&Bl[bn][bk0 + c * 4]) = lv;
      }
    }
    __syncthreads();
    short8 ah[4], al[4], bh[4], bl[4];
#pragma unroll
    for (int i = 0; i < 4; i++) {
      ah[i] = *reinterpret_cast<const short8*>(&Ah[wm + i * 16 + m_in][kgrp * 8]);
      al[i] = *reinterpret_cast<const short8*>(&Al[wm + i * 16 + m_in][kgrp * 8]);
    }
#pragma unroll
    for (int j = 0; j < 4; j++) {
      bh[j] = *reinterpret_cast<const short8*>(&Bh[wn + j * 16 + m_in][kgrp * 8]);
      bl[j] = *reinterpret_cast<const short8*>(&Bl[wn + j * 16 + m_in][kgrp * 8]);
    }
#pragma unroll
    for (int i = 0; i < 4; i++)
#pragma unroll
      for (int j = 0; j < 4; j++) {
        acc[i][j] = __builtin_amdgcn_mfma_f32_16x16x32_bf16(ah[i], bh[j], acc[i][j], 0, 0, 0);
        acc[i][j] = __builtin_amdgcn_mfma_f32_16x16x32_bf16(ah[i], bl[j], acc[i][j], 0, 0, 0);
        acc[i][j] = __builtin_amdgcn_mfma_f32_16x16x32_bf16(al[i], bh[j], acc[i][j], 0, 0, 0);
      }
    __syncthreads();
  }
#pragma unroll
  for (int i = 0; i < 4; i++)
#pragma unroll
    for (int j = 0; j < 4; j++)
#pragma unroll
      for (int r = 0; r < 4; r++) {
        int row = m0 + wm + i * 16 + kgrp * 4 + r;
        int col = n0 + wn + j * 16 + m_in;
        C[(size_t)row * N + col] = acc[i][j][r];
      }
}

// ---------------- norm + rope (unchanged) ----------------
__global__ __launch_bounds__(256)
void norm_rope_kernel(const float* __restrict__ in, float* __restrict__ out,
                      const float* __restrict__ w, const float* __restrict__ cosb,
                      const float* __restrict__ sinb, int H, int do_rope,
                      int transpose_out) {
  const int sq = blockIdx.x / H;
  const int h = blockIdx.x % H;
  const int d = threadIdx.x;
  float x = in[((size_t)sq * H + h) * HD + d];
  float v = x * x;
#pragma unroll
  for (int off = 32; off; off >>= 1) v += __shfl_down(v, off);
  __shared__ float red[4];
  __shared__ float sscale;
  if ((d & 63) == 0) red[d >> 6] = v;
  __syncthreads();
  if (d == 0)
    sscale = rsqrtf((red[0] + red[1] + red[2] + red[3]) * (1.0f / HD) + 1e-6f);
  __syncthreads();
  float n = x * sscale;
  if (w) n *= w[d];
  if (do_rope) {
    __shared__ float nb[HD];
    nb[d] = n;
    __syncthreads();
    float other = (d < HD / 2) ? -nb[d + HD / 2] : nb[d - HD / 2];
    n = n * cosb[(size_t)sq * HD + d] + other * sinb[(size_t)sq * HD + d];
  }
  if (transpose_out)
    out[((size_t)h * HD + d) * S_LEN + sq] = n;
  else
    out[((size_t)sq * H + h) * HD + d] = n;
}

// ---------------- MFMA flash attention ----------------
// Block = (64-query tile, q-head). 4 waves, wave w owns q rows [16w,16w+16).
// K row-major [s][kvh][d]; V pre-transposed vT[kvh][d][s].
// QK^T: split-bf16 3-product (fp32-accurate scores). PV: P bf16 x V split.
// LDS (dynamic, 147 KB): Kh/Kl [64][264], Vh/Vl [256][72], Ps [64][72].
#define KSTR 264
#define VSTR 72
#define PSTR 72
__global__ __launch_bounds__(256, 1)
void flash_attn(const float* __restrict__ qn, const float* __restrict__ kn,
                const float* __restrict__ vT, float* __restrict__ ctx) {
  extern __shared__ char smem[];
  short* Kh = (short*)smem;                  // 64*264*2 = 33792 B
  short* Kl = (short*)(smem + 33792);
  short* Vh = (short*)(smem + 67584);        // 256*72*2 = 36864 B
  short* Vl = (short*)(smem + 104448);
  short* Ps = (short*)(smem + 141312);       // 64*72*2  = 9216 B

  const int qt = blockIdx.x, h = blockIdx.y;
  const int kvh = h >> 1;  // NH/NKV = 2
  const int q0 = qt * 64;
  const int tid = threadIdx.x;
  const int w = tid >> 6, lane = tid & 63;
  const int quad = lane >> 4, col = lane & 15;

  // ---- Q fragments (A-layout: m=lane&15, k=quad*8+j), split bf16 ----
  short8 qh[8], ql[8];
  {
    const float* qrow = qn + ((size_t)(q0 + w * 16 + col) * NH + h) * HD;
#pragma unroll
    for (int s8 = 0; s8 < 8; s8++) {
      int d0 = s8 * 32 + quad * 8;
      float4_t a = *reinterpret_cast<const float4_t*>(qrow + d0);
      float4_t b = *reinterpret_cast<const float4_t*>(qrow + d0 + 4);
#pragma unroll
      for (int e = 0; e < 4; e++) {
        short hh, ll;
        split2(a[e], hh, ll);
        qh[s8][e] = hh; ql[s8][e] = ll;
        split2(b[e], hh, ll);
        qh[s8][4 + e] = hh; ql[s8][4 + e] = ll;
      }
    }
  }

  f32x4 o[16];
#pragma unroll
  for (int i = 0; i < 16; i++) o[i] = (f32x4){0.f, 0.f, 0.f, 0.f};
  float m_r[4] = {-INFINITY, -INFINITY, -INFINITY, -INFINITY};
  float l_r[4] = {0.f, 0.f, 0.f, 0.f};

  const int lo_t = (q0 > 1023) ? ((q0 - 1023) >> 6) : 0;
  const int hi_t = q0 >> 6;

  for (int kt = lo_t; kt <= hi_t; kt++) {
    const int kt0 = kt << 6;
    __syncthreads();  // previous tile's fragment reads complete
    // ---- stage K tile [key][d], coalesced float4, split hi/lo ----
    {
      const int r0 = tid >> 6;
      const int c4 = (tid & 63) * 4;
#pragma unroll
      for (int i = 0; i < 16; i++) {
        int row = r0 + i * 4;
        float4_t kv4 = *reinterpret_cast<const float4_t*>(
            kn + ((size_t)(kt0 + row) * NKV + kvh) * HD + c4);
        short4_t hv, lv;
#pragma unroll
        for (int e = 0; e < 4; e++) {
          short hh, ll;
          split2(kv4[e], hh, ll);
          hv[e] = hh; lv[e] = ll;
        }
        *reinterpret_cast<short4_t*>(Kh + row * KSTR + c4) = hv;
        *reinterpret_cast<short4_t*>(Kl + row * KSTR + c4) = lv;
      }
    }
    // ---- stage V^T tile [d][key] from vT (coalesced in s), split ----
    {
      const int dbase = tid >> 4;
      const int k4 = (tid & 15) * 4;
#pragma unroll
      for (int i = 0; i < 16; i++) {
        int d = dbase + i * 16;
        float4_t vv = *reinterpret_cast<const float4_t*>(
            vT + ((size_t)kvh * HD + d) * S_LEN + kt0 + k4);
        short4_t hv, lv;
#pragma unroll
        for (int e = 0; e < 4; e++) {
          short hh, ll;
          split2(vv[e], hh, ll);
          hv[e] = hh; lv[e] = ll;
        }
        *reinterpret_cast<short4_t*>(Vh + d * VSTR + k4) = hv;
        *reinterpret_cast<short4_t*>(Vl + d * VSTR + k4) = lv;
      }
    }
    __syncthreads();
    // ---- QK^T: 4 n-tiles of 16 keys, 8 k-steps, 3-product split ----
    f32x4 sc[4];
#pragma unroll
    for (int nt = 0; nt < 4; nt++) sc[nt] = (f32x4){0.f, 0.f, 0.f, 0.f};
#pragma unroll
    for (int s8 = 0; s8 < 8; s8++) {
#pragma unroll
      for (int nt = 0; nt < 4; nt++) {
        const short8 bh = *reinterpret_cast<const short8*>(
            Kh + (nt * 16 + col) * KSTR + s8 * 32 + quad * 8);
        const short8 bl = *reinterpret_cast<const short8*>(
            Kl + (nt * 16 + col) * KSTR + s8 * 32 + quad * 8);
        sc[nt] = __builtin_amdgcn_mfma_f32_16x16x32_bf16(qh[s8], bh, sc[nt], 0, 0, 0);
        sc[nt] = __builtin_amdgcn_mfma_f32_16x16x32_bf16(qh[s8], bl, sc[nt], 0, 0, 0);
        sc[nt] = __builtin_amdgcn_mfma_f32_16x16x32_bf16(ql[s8], bh, sc[nt], 0, 0, 0);
      }
    }
    // ---- mask + online softmax (C-layout: row=quad*4+r, col=nt*16+col) ----
#pragma unroll
    for (int r = 0; r < 4; r++) {
      const int q_abs = q0 + w * 16 + quad * 4 + r;
      // mask
#pragma unroll
      for (int nt = 0; nt < 4; nt++) {
        int k_abs = kt0 + nt * 16 + col;
        bool valid = (k_abs <= q_abs) && (q_abs - k_abs < WINDOW);
        if (!valid) sc[nt][r] = -INFINITY;
      }
      float mx = fmaxf(fmaxf(sc[0][r], sc[1][r]), fmaxf(sc[2][r], sc[3][r]));
      mx = fmaxf(mx, __shfl_xor(mx, 1));
      mx = fmaxf(mx, __shfl_xor(mx, 2));
      mx = fmaxf(mx, __shfl_xor(mx, 4));
      mx = fmaxf(mx, __shfl_xor(mx, 8));
      float mn = fmaxf(m_r[r], mx);
      float alpha = (mn == -INFINITY) ? 1.f : __expf(m_r[r] - mn);
      m_r[r] = mn;
      float rsum = 0.f;
#pragma unroll
      for (int nt = 0; nt < 4; nt++) {
        float s = sc[nt][r];
        float e = (s == -INFINITY) ? 0.f : __expf(s - mn);
        rsum += e;
        Ps[(size_t)(w * 16 + quad * 4 + r) * PSTR + nt * 16 + col] = bf16_rne(e);
      }
      rsum += __shfl_xor(rsum, 1);
      rsum += __shfl_xor(rsum, 2);
      rsum += __shfl_xor(rsum, 4);
      rsum += __shfl_xor(rsum, 8);
      l_r[r] = l_r[r] * alpha + rsum;
#pragma unroll
      for (int nt2 = 0; nt2 < 16; nt2++) o[nt2][r] *= alpha;
    }
    __syncthreads();  // P visible; K/V still live for PV
    // ---- PV: A = P (bf16), B = V split (2-product), 16 d-tiles x 2 ksteps ----
#pragma unroll
    for (int ks = 0; ks < 2; ks++) {
      const short8 pa = *reinterpret_cast<const short8*>(
          Ps + (size_t)(w * 16 + col) * PSTR + ks * 32 + quad * 8);
#pragma unroll
      for (int nt = 0; nt < 16; nt++) {
        const short8 vh = *reinterpret_cast<const short8*>(
            Vh + (size_t)(nt * 16 + col) * VSTR + ks * 32 + quad * 8);
        const short8 vl = *reinterpret_cast<const short8*>(
            Vl + (size_t)(nt * 16 + col) * VSTR + ks * 32 + quad * 8);
        o[nt] = __builtin_amdgcn_mfma_f32_16x16x32_bf16(pa, vh, o[nt], 0, 0, 0);
        o[nt] = __builtin_amdgcn_mfma_f32_16x16x32_bf16(pa, vl, o[nt], 0, 0, 0);
      }
    }
  }
  // ---- epilogue ----
#pragma unroll
  for (int r = 0; r < 4; r++) {
    const float inv = 1.0f / l_r[r];
    const int row = q0 + w * 16 + quad * 4 + r;
#pragma unroll
    for (int nt = 0; nt < 16; nt++)
      ctx[((size_t)row * NH + h) * HD + nt * 16 + col] = o[nt][r] * inv;
  }
}

extern "C" void kernel_launch(void* const* d_in, const int* in_sizes, int n_in,
                              void* d_out, int out_size, void* d_ws, size_t ws_size,
                              hipStream_t stream) {
  const float* hs   = (const float*)d_in[0];
  const float* cosb = (const float*)d_in[1];
  const float* sinb = (const float*)d_in[2];
  const float* wq   = (const float*)d_in[3];
  const float* wk   = (const float*)d_in[4];
  const float* wv   = (const float*)d_in[5];
  const float* wo   = (const float*)d_in[6];
  const float* wo_  = wo; (void)wo_;
  const float* qw   = (const float*)d_in[7];
  const float* kw   = (const float*)d_in[8];

  // fp32 workspace, 32 MB total (proven footprint), aliased by lifetime:
  //   qc : q rows -> ctx rows (16 MB)
  //   X  : v GEMM out, then k GEMM out + k-norm in place (8 MB)
  //   vT : v normed, transposed [kvh][d][s] (8 MB)
  float* qc = (float*)((char*)d_ws + 256);
  float* X  = qc + (size_t)S_LEN * NH * HD;
  float* vT = X + (size_t)S_LEN * NKV * HD;

  dim3 blk(256);
  // allow 147 KB dynamic LDS for flash_attn (idempotent, graph-capture safe)
  (void)hipFuncSetAttribute((const void*)flash_attn,
                            hipFuncAttributeMaxDynamicSharedMemorySize, 150528);

  // v projection -> X, then norm + transpose -> vT
  gemm_mfma<<<dim3((NKV * HD) / 128, S_LEN / 128), blk, 0, stream>>>(
      hs, wv, X, S_LEN, NKV * HD, HID);
  norm_rope_kernel<<<S_LEN * NKV, blk, 0, stream>>>(X, vT, nullptr, nullptr,
                                                    nullptr, NKV, 0, 1);
  // k projection -> X (vraw dead), norm+rope in place
  gemm_mfma<<<dim3((NKV * HD) / 128, S_LEN / 128), blk, 0, stream>>>(
      hs, wk, X, S_LEN, NKV * HD, HID);
  norm_rope_kernel<<<S_LEN * NKV, blk, 0, stream>>>(X, X, kw, cosb, sinb,
                                                    NKV, 1, 0);
  // q projection -> qc, norm+rope in place
  gemm_mfma<<<dim3((NH * HD) / 128, S_LEN / 128), blk, 0, stream>>>(
      hs, wq, qc, S_LEN, NH * HD, HID);
  norm_rope_kernel<<<S_LEN * NH, blk, 0, stream>>>(qc, qc, qw, cosb, sinb,
                                                   NH, 1, 0);
  // flash attention: (q-tile, head) grid; ctx overwrites qc (block-local rows)
  flash_attn<<<dim3(S_LEN / 64, NH), blk, 150528, stream>>>(qc, X, vT, qc);
  // output projection
  gemm_mfma<<<dim3(HID / 128, S_LEN / 128), blk, 0, stream>>>(
      qc, wo, (float*)d_out, S_LEN, HID, NH * HD);
}

// Round 7
// 629.404 us; speedup vs baseline: 3.4504x; 1.5445x over previous
//
#include <hip/hip_runtime.h>
#include <hip/hip_bf16.h>
#include <math.h>

#define S_LEN 2048
#define HID 2560
#define NH 8
#define NKV 4
#define HD 256
#define WINDOW 1024

typedef short short8 __attribute__((ext_vector_type(8)));
typedef short short4_t __attribute__((ext_vector_type(4)));
typedef float f32x4 __attribute__((ext_vector_type(4)));
typedef float float4_t __attribute__((ext_vector_type(4)));

// round-to-nearest-even fp32 -> bf16 bits
__device__ __forceinline__ short bf16_rne(float x) {
  unsigned u = __float_as_uint(x);
  return (short)((u + 0x7FFFu + ((u >> 16) & 1u)) >> 16);
}
// split x = hi + lo (both bf16); hi*hi + hi*lo + lo*hi ~ fp32-accurate product
__device__ __forceinline__ void split2(float x, short &h, short &l) {
  unsigned u = __float_as_uint(x);
  unsigned hb = (u + 0x7FFFu + ((u >> 16) & 1u)) & 0xFFFF0000u;
  h = (short)(hb >> 16);
  float r = x - __uint_as_float(hb);
  l = bf16_rne(r);
}

// ---------------- GEMM body (round-5 proven, shared by two kernels) --------
struct GemmSmem {
  short Ah[128][32], Al[128][32], Bh[128][32], Bl[128][32];
};

__device__ __forceinline__ void gemm_body(GemmSmem* sm, const float* __restrict__ A,
                                          const float* __restrict__ B,
                                          float* __restrict__ C, int M, int N,
                                          int K, int m0, int n0) {
  const int tid = threadIdx.x;
  const int wave = tid >> 6, lane = tid & 63;
  const int wm = (wave >> 1) * 64, wn = (wave & 1) * 64;
  const int m_in = lane & 15, kgrp = lane >> 4;
  const int bn = tid & 127;
  const int bk0 = (tid >> 7) * 16;

  f32x4 acc[4][4];
#pragma unroll
  for (int i = 0; i < 4; i++)
#pragma unroll
    for (int j = 0; j < 4; j++) acc[i][j] = (f32x4){0.f, 0.f, 0.f, 0.f};

  for (int k0 = 0; k0 < K; k0 += 32) {
#pragma unroll
    for (int i = 0; i < 4; i++) {
      int f = tid + i * 256;
      int m = f >> 3, c4 = (f & 7) << 2;
      float4_t av = *reinterpret_cast<const float4_t*>(
          &A[(size_t)(m0 + m) * K + (k0 + c4)]);
      short4_t hv, lv;
#pragma unroll
      for (int e = 0; e < 4; e++) {
        short h, l;
        split2(av[e], h, l);
        hv[e] = h; lv[e] = l;
      }
      *reinterpret_cast<short4_t*>(&sm->Ah[m][c4]) = hv;
      *reinterpret_cast<short4_t*>(&sm->Al[m][c4]) = lv;
    }
    {
      const float* bp = &B[(size_t)(k0 + bk0) * N + (n0 + bn)];
      float vals[16];
#pragma unroll
      for (int kk = 0; kk < 16; kk++) vals[kk] = bp[(size_t)kk * N];
#pragma unroll
      for (int c = 0; c < 4; c++) {
        short4_t hv, lv;
#pragma unroll
        for (int e = 0; e < 4; e++) {
          short h, l;
          split2(vals[c * 4 + e], h, l);
          hv[e] = h; lv[e] = l;
        }
        *reinterpret_cast<short4_t*>(&sm->Bh[bn][bk0 + c * 4]) = hv;
        *reinterpret_cast<short4_t*>(&sm->Bl[bn][bk0 + c * 4]) = lv;
      }
    }
    __syncthreads();
    short8 ah[4], al[4], bh[4], bl[4];
#pragma unroll
    for (int i = 0; i < 4; i++) {
      ah[i] = *reinterpret_cast<const short8*>(&sm->Ah[wm + i * 16 + m_in][kgrp * 8]);
      al[i] = *reinterpret_cast<const short8*>(&sm->Al[wm + i * 16 + m_in][kgrp * 8]);
    }
#pragma unroll
    for (int j = 0; j < 4; j++) {
      bh[j] = *reinterpret_cast<const short8*>(&sm->Bh[wn + j * 16 + m_in][kgrp * 8]);
      bl[j] = *reinterpret_cast<const short8*>(&sm->Bl[wn + j * 16 + m_in][kgrp * 8]);
    }
#pragma unroll
    for (int i = 0; i < 4; i++)
#pragma unroll
      for (int j = 0; j < 4; j++) {
        acc[i][j] = __builtin_amdgcn_mfma_f32_16x16x32_bf16(ah[i], bh[j], acc[i][j], 0, 0, 0);
        acc[i][j] = __builtin_amdgcn_mfma_f32_16x16x32_bf16(ah[i], bl[j], acc[i][j], 0, 0, 0);
        acc[i][j] = __builtin_amdgcn_mfma_f32_16x16x32_bf16(al[i], bh[j], acc[i][j], 0, 0, 0);
      }
    __syncthreads();
  }
#pragma unroll
  for (int i = 0; i < 4; i++)
#pragma unroll
    for (int j = 0; j < 4; j++)
#pragma unroll
      for (int r = 0; r < 4; r++) {
        int row = m0 + wm + i * 16 + kgrp * 4 + r;
        int col = n0 + wn + j * 16 + m_in;
        C[(size_t)row * N + col] = acc[i][j][r];
      }
}

__global__ __launch_bounds__(256)
void gemm_mfma(const float* __restrict__ A, const float* __restrict__ B,
               float* __restrict__ C, int M, int N, int K) {
  __shared__ GemmSmem sm;
  gemm_body(&sm, A, B, C, M, N, K, blockIdx.y * 128, blockIdx.x * 128);
}

// k and v projections fused into one dispatch (each alone under-fills the GPU)
__global__ __launch_bounds__(256)
void gemm_mfma_kv(const float* __restrict__ A, const float* __restrict__ B0,
                  const float* __restrict__ B1, float* __restrict__ C0,
                  float* __restrict__ C1, int M, int N, int K) {
  __shared__ GemmSmem sm;
  const int nb = N / 128;
  const int half = blockIdx.x >= nb;
  gemm_body(&sm, A, half ? B1 : B0, half ? C1 : C0, M, N, K,
            blockIdx.y * 128, (blockIdx.x - half * nb) * 128);
}

// ---------------- norms ----------------
// q: fp32 in-place, rms+weight+rope
__global__ __launch_bounds__(256)
void qnorm_kernel(float* __restrict__ io, const float* __restrict__ w,
                  const float* __restrict__ cosb, const float* __restrict__ sinb) {
  const int sq = blockIdx.x / NH;
  const int h = blockIdx.x % NH;
  const int d = threadIdx.x;
  float x = io[((size_t)sq * NH + h) * HD + d];
  float v = x * x;
#pragma unroll
  for (int off = 32; off; off >>= 1) v += __shfl_down(v, off);
  __shared__ float red[4];
  __shared__ float sscale;
  __shared__ float nb[HD];
  if ((d & 63) == 0) red[d >> 6] = v;
  __syncthreads();
  if (d == 0)
    sscale = rsqrtf((red[0] + red[1] + red[2] + red[3]) * (1.0f / HD) + 1e-6f);
  __syncthreads();
  float n = x * sscale * w[d];
  nb[d] = n;
  __syncthreads();
  float other = (d < HD / 2) ? -nb[d + HD / 2] : nb[d - HD / 2];
  n = n * cosb[(size_t)sq * HD + d] + other * sinb[(size_t)sq * HD + d];
  io[((size_t)sq * NH + h) * HD + d] = n;
}

// k: rms+weight+rope, then pre-split to kh/kl bf16 [s][kvh][d]
__global__ __launch_bounds__(256)
void knorm_split_kernel(const float* __restrict__ in, short* __restrict__ kh,
                        short* __restrict__ kl, const float* __restrict__ w,
                        const float* __restrict__ cosb,
                        const float* __restrict__ sinb) {
  const int sq = blockIdx.x / NKV;
  const int h = blockIdx.x % NKV;
  const int d = threadIdx.x;
  float x = in[((size_t)sq * NKV + h) * HD + d];
  float v = x * x;
#pragma unroll
  for (int off = 32; off; off >>= 1) v += __shfl_down(v, off);
  __shared__ float red[4];
  __shared__ float sscale;
  __shared__ float nb[HD];
  if ((d & 63) == 0) red[d >> 6] = v;
  __syncthreads();
  if (d == 0)
    sscale = rsqrtf((red[0] + red[1] + red[2] + red[3]) * (1.0f / HD) + 1e-6f);
  __syncthreads();
  float n = x * sscale * w[d];
  nb[d] = n;
  __syncthreads();
  float other = (d < HD / 2) ? -nb[d + HD / 2] : nb[d - HD / 2];
  n = n * cosb[(size_t)sq * HD + d] + other * sinb[(size_t)sq * HD + d];
  short hh, ll;
  split2(n, hh, ll);
  kh[((size_t)sq * NKV + h) * HD + d] = hh;
  kl[((size_t)sq * NKV + h) * HD + d] = ll;
}

// v: rms norm, bf16, transposed to vtb[kvh][d][s]
__global__ __launch_bounds__(256)
void vnormT_kernel(const float* __restrict__ in, short* __restrict__ vtb) {
  const int sq = blockIdx.x / NKV;
  const int h = blockIdx.x % NKV;
  const int d = threadIdx.x;
  float x = in[((size_t)sq * NKV + h) * HD + d];
  float v = x * x;
#pragma unroll
  for (int off = 32; off; off >>= 1) v += __shfl_down(v, off);
  __shared__ float red[4];
  __shared__ float sscale;
  if ((d & 63) == 0) red[d >> 6] = v;
  __syncthreads();
  if (d == 0)
    sscale = rsqrtf((red[0] + red[1] + red[2] + red[3]) * (1.0f / HD) + 1e-6f);
  __syncthreads();
  vtb[((size_t)h * HD + d) * S_LEN + sq] = bf16_rne(x * sscale);
}

// ---------------- flash attention v2 (split-k, pre-split inputs) -----------
// Grid (32 q-tiles, NH, 2 splits). Block = 256 thr / 4 waves; wave w owns q
// rows [16w,16w+16). 32-key k-tiles. Static LDS 59.4 KB -> 2 blocks/CU.
// QK^T: (qh+ql) x (kh+kl) 3-product (fp32-accurate). PV: P bf16 x V bf16.
// Outputs UNNORMALIZED o + per-row (m,l) for the combine pass.
__global__ __launch_bounds__(256, 2)
void flash_attn2(const float* __restrict__ qn, const short* __restrict__ kh,
                 const short* __restrict__ kl, const short* __restrict__ vtb,
                 float* __restrict__ oA, float* __restrict__ oB,
                 float* __restrict__ mlA, float* __restrict__ mlB) {
  __shared__ short Kh[32][264], Kl[32][264];  // [key][d], pad 8
  __shared__ short Vb[256][40];               // [d][key], pad 8
  __shared__ short Ps[64][40];                // [q][key], pad 8

  const int qt = blockIdx.x, h = blockIdx.y, sp = blockIdx.z;
  const int kvh = h >> 1;  // NH/NKV = 2
  const int q0 = qt * 64;
  const int tid = threadIdx.x;
  const int w = tid >> 6, lane = tid & 63;
  const int quad = lane >> 4, col = lane & 15;

  float* oOut = sp ? oB : oA;
  float* mlOut = sp ? mlB : mlA;

  // Q fragments (A-layout: m=col, k=quad*8+j), split bf16, read once
  short8 qh[8], ql[8];
  {
    const float* qrow = qn + ((size_t)(q0 + w * 16 + col) * NH + h) * HD;
#pragma unroll
    for (int s8 = 0; s8 < 8; s8++) {
      int d0 = s8 * 32 + quad * 8;
      float4_t a = *reinterpret_cast<const float4_t*>(qrow + d0);
      float4_t b = *reinterpret_cast<const float4_t*>(qrow + d0 + 4);
#pragma unroll
      for (int e = 0; e < 4; e++) {
        short hh, ll;
        split2(a[e], hh, ll);
        qh[s8][e] = hh; ql[s8][e] = ll;
        split2(b[e], hh, ll);
        qh[s8][4 + e] = hh; ql[s8][4 + e] = ll;
      }
    }
  }

  f32x4 o[16];
#pragma unroll
  for (int i = 0; i < 16; i++) o[i] = (f32x4){0.f, 0.f, 0.f, 0.f};
  float m_r[4] = {-INFINITY, -INFINITY, -INFINITY, -INFINITY};
  float l_r[4] = {0.f, 0.f, 0.f, 0.f};

  // k-tile range for this q-tile, split in two halves across blockIdx.z
  const int lo_t = (q0 > 1023) ? ((q0 - 1023) >> 5) : 0;
  const int hi_t = (q0 + 63) >> 5;
  const int halfn = (hi_t - lo_t + 2) >> 1;
  const int t0 = sp ? (lo_t + halfn) : lo_t;
  const int t1 = sp ? hi_t : (lo_t + halfn - 1);

  for (int kt = t0; kt <= t1; kt++) {
    const int kt0 = kt << 5;
    __syncthreads();  // previous tile's LDS reads complete
    // stage K hi/lo: 32 rows x 256 shorts each (pure copies, pre-split)
#pragma unroll
    for (int i = 0; i < 4; i++) {
      int idx = tid + i * 256;
      int row = idx >> 5, g = idx & 31;
      size_t gofs = ((size_t)(kt0 + row) * NKV + kvh) * HD + g * 8;
      *reinterpret_cast<short8*>(&Kh[row][g * 8]) =
          *reinterpret_cast<const short8*>(kh + gofs);
      *reinterpret_cast<short8*>(&Kl[row][g * 8]) =
          *reinterpret_cast<const short8*>(kl + gofs);
    }
    // stage V: 256 d x 32 keys (bf16 single)
#pragma unroll
    for (int i = 0; i < 4; i++) {
      int idx = tid + i * 256;
      int d = idx >> 2, g = idx & 3;
      *reinterpret_cast<short8*>(&Vb[d][g * 8]) = *reinterpret_cast<const short8*>(
          vtb + ((size_t)kvh * HD + d) * S_LEN + kt0 + g * 8);
    }
    __syncthreads();
    // QK^T: 2 n-tiles x 8 k-steps x 3 products
    f32x4 sc[2];
    sc[0] = (f32x4){0.f, 0.f, 0.f, 0.f};
    sc[1] = (f32x4){0.f, 0.f, 0.f, 0.f};
#pragma unroll
    for (int s8 = 0; s8 < 8; s8++) {
#pragma unroll
      for (int nt = 0; nt < 2; nt++) {
        const short8 bh = *reinterpret_cast<const short8*>(
            &Kh[nt * 16 + col][s8 * 32 + quad * 8]);
        const short8 bl = *reinterpret_cast<const short8*>(
            &Kl[nt * 16 + col][s8 * 32 + quad * 8]);
        sc[nt] = __builtin_amdgcn_mfma_f32_16x16x32_bf16(qh[s8], bh, sc[nt], 0, 0, 0);
        sc[nt] = __builtin_amdgcn_mfma_f32_16x16x32_bf16(qh[s8], bl, sc[nt], 0, 0, 0);
        sc[nt] = __builtin_amdgcn_mfma_f32_16x16x32_bf16(ql[s8], bh, sc[nt], 0, 0, 0);
      }
    }
    // mask + online softmax (C-layout: row=quad*4+r, col=nt*16+col)
#pragma unroll
    for (int r = 0; r < 4; r++) {
      const int q_abs = q0 + w * 16 + quad * 4 + r;
#pragma unroll
      for (int nt = 0; nt < 2; nt++) {
        int k_abs = kt0 + nt * 16 + col;
        bool valid = (k_abs <= q_abs) && (q_abs - k_abs < WINDOW);
        if (!valid) sc[nt][r] = -INFINITY;
      }
      float mx = fmaxf(sc[0][r], sc[1][r]);
      mx = fmaxf(mx, __shfl_xor(mx, 1));
      mx = fmaxf(mx, __shfl_xor(mx, 2));
      mx = fmaxf(mx, __shfl_xor(mx, 4));
      mx = fmaxf(mx, __shfl_xor(mx, 8));
      float mn = fmaxf(m_r[r], mx);
      float alpha = (mn == -INFINITY) ? 1.f : __expf(m_r[r] - mn);
      m_r[r] = mn;
      float rsum = 0.f;
#pragma unroll
      for (int nt = 0; nt < 2; nt++) {
        float s = sc[nt][r];
        float e = (s == -INFINITY) ? 0.f : __expf(s - mn);
        rsum += e;
        Ps[w * 16 + quad * 4 + r][nt * 16 + col] = bf16_rne(e);
      }
      rsum += __shfl_xor(rsum, 1);
      rsum += __shfl_xor(rsum, 2);
      rsum += __shfl_xor(rsum, 4);
      rsum += __shfl_xor(rsum, 8);
      l_r[r] = l_r[r] * alpha + rsum;
#pragma unroll
      for (int nt2 = 0; nt2 < 16; nt2++) o[nt2][r] *= alpha;
    }
    __syncthreads();  // P visible before PV
    // PV: K=32 -> one k-step, 16 d-tiles, V single product
    {
      const short8 pa = *reinterpret_cast<const short8*>(&Ps[w * 16 + col][quad * 8]);
#pragma unroll
      for (int nt = 0; nt < 16; nt++) {
        const short8 vb = *reinterpret_cast<const short8*>(&Vb[nt * 16 + col][quad * 8]);
        o[nt] = __builtin_amdgcn_mfma_f32_16x16x32_bf16(pa, vb, o[nt], 0, 0, 0);
      }
    }
  }
  // epilogue: unnormalized o + (m,l)
#pragma unroll
  for (int r = 0; r < 4; r++) {
    const int row = q0 + w * 16 + quad * 4 + r;
    const size_t base = ((size_t)row * NH + h) * HD;
#pragma unroll
    for (int nt = 0; nt < 16; nt++) oOut[base + nt * 16 + col] = o[nt][r];
    if (col == 0) {
      mlOut[((size_t)row * NH + h) * 2] = m_r[r];
      mlOut[((size_t)row * NH + h) * 2 + 1] = l_r[r];
    }
  }
}

// merge the two k-splits: ctx = (eA*oA + eB*oB) / (eA*lA + eB*lB)
__global__ __launch_bounds__(256)
void combine_kernel(const float* __restrict__ oA, const float* __restrict__ oB,
                    const float* __restrict__ mlA, const float* __restrict__ mlB,
                    float* __restrict__ ctx) {
  const int idx = blockIdx.x;  // s*NH + h
  const int d = threadIdx.x;
  const float mA = mlA[(size_t)idx * 2], lA = mlA[(size_t)idx * 2 + 1];
  const float mB = mlB[(size_t)idx * 2], lB = mlB[(size_t)idx * 2 + 1];
  const float m = fmaxf(mA, mB);
  const float eA = (mA == -INFINITY) ? 0.f : __expf(mA - m);
  const float eB = (mB == -INFINITY) ? 0.f : __expf(mB - m);
  const float inv = 1.0f / (eA * lA + eB * lB);
  const size_t b = (size_t)idx * HD + d;
  ctx[b] = (eA * oA[b] + eB * oB[b]) * inv;
}

extern "C" void kernel_launch(void* const* d_in, const int* in_sizes, int n_in,
                              void* d_out, int out_size, void* d_ws, size_t ws_size,
                              hipStream_t stream) {
  const float* hs   = (const float*)d_in[0];
  const float* cosb = (const float*)d_in[1];
  const float* sinb = (const float*)d_in[2];
  const float* wq   = (const float*)d_in[3];
  const float* wk   = (const float*)d_in[4];
  const float* wv   = (const float*)d_in[5];
  const float* wo   = (const float*)d_in[6];
  const float* qw   = (const float*)d_in[7];
  const float* kw   = (const float*)d_in[8];

  // workspace layout (44.5 MB):
  //   qc  : q normed fp32 [S][NH][HD] -> later ctx (combine output)   16 MB
  //   Xk  : k GEMM out fp32 (dead after knorm_split)                   8 MB
  //   Xv  : v GEMM out fp32 (dead after vnormT)                        8 MB
  //   oA  : split-0 partial o fp32, ALIASES Xk+Xv (16 MB)
  //   kh/kl : pre-split K bf16 [S][NKV][HD]                        4+4 MB
  //   vtb : V bf16 transposed [kvh][d][s]                             4 MB
  //   mlA/mlB : per-row (m,l) fp32                               2x128 KB
  //   oB  : split-1 partial o -> lives in d_out (dead until out-proj)
  float* qc  = (float*)((char*)d_ws + 256);
  float* Xk  = qc + (size_t)S_LEN * NH * HD;
  float* Xv  = Xk + (size_t)S_LEN * NKV * HD;
  float* oA  = Xk;  // alias: 16 MB spanning Xk+Xv, both dead before flash
  short* kh  = (short*)(Xv + (size_t)S_LEN * NKV * HD);
  short* kl  = kh + (size_t)S_LEN * NKV * HD;
  short* vtb = kl + (size_t)S_LEN * NKV * HD;
  float* mlA = (float*)(vtb + (size_t)S_LEN * NKV * HD);
  float* mlB = mlA + (size_t)S_LEN * NH * 2;
  float* oB  = (float*)d_out;

  dim3 blk(256);
  // k+v projections fused (one 256-block dispatch), then prep kernels
  gemm_mfma_kv<<<dim3(16, S_LEN / 128), blk, 0, stream>>>(
      hs, wk, wv, Xk, Xv, S_LEN, NKV * HD, HID);
  knorm_split_kernel<<<S_LEN * NKV, blk, 0, stream>>>(Xk, kh, kl, kw, cosb, sinb);
  vnormT_kernel<<<S_LEN * NKV, blk, 0, stream>>>(Xv, vtb);
  // q projection + norm/rope
  gemm_mfma<<<dim3((NH * HD) / 128, S_LEN / 128), blk, 0, stream>>>(
      hs, wq, qc, S_LEN, NH * HD, HID);
  qnorm_kernel<<<S_LEN * NH, blk, 0, stream>>>(qc, qw, cosb, sinb);
  // flash attention, split-k x2 (oA overlays dead Xk/Xv; oB in d_out)
  flash_attn2<<<dim3(S_LEN / 64, NH, 2), blk, 0, stream>>>(
      qc, kh, kl, vtb, oA, oB, mlA, mlB);
  // combine partials -> ctx (into qc; q data dead after flash)
  combine_kernel<<<S_LEN * NH, blk, 0, stream>>>(oA, oB, mlA, mlB, qc);
  // output projection (overwrites d_out / oB)
  gemm_mfma<<<dim3(HID / 128, S_LEN / 128), blk, 0, stream>>>(
      qc, wo, (float*)d_out, S_LEN, HID, NH * HD);
}

// Round 8
// 503.744 us; speedup vs baseline: 4.3111x; 1.2495x over previous
//
#include <hip/hip_runtime.h>
#include <hip/hip_bf16.h>
#include <math.h>

#define S_LEN 2048
#define HID 2560
#define NH 8
#define NKV 4
#define HD 256
#define WINDOW 1024

typedef short short8 __attribute__((ext_vector_type(8)));
typedef short short4_t __attribute__((ext_vector_type(4)));
typedef float f32x4 __attribute__((ext_vector_type(4)));
typedef float float4_t __attribute__((ext_vector_type(4)));

__device__ __forceinline__ short bf16_rne(float x) {
  unsigned u = __float_as_uint(x);
  return (short)((u + 0x7FFFu + ((u >> 16) & 1u)) >> 16);
}
__device__ __forceinline__ void split2(float x, short &h, short &l) {
  unsigned u = __float_as_uint(x);
  unsigned hb = (u + 0x7FFFu + ((u >> 16) & 1u)) & 0xFFFF0000u;
  h = (short)(hb >> 16);
  float r = x - __uint_as_float(hb);
  l = bf16_rne(r);
}

// ================= PLAN A: pre-split GEMM =================
// A [M][K] hi/lo bf16 row-major; B [N][K] hi/lo bf16 (pre-transposed).
// C fp32 [M][N]. Tile 64(M)x128(N)x64(K). 256 thr / 4 waves (2x2), wave
// tile 32x64 = 2x4 of 16x16x32 MFMA, 3-product split accumulation.
// LDS XOR-swizzle: granule g (8 shorts) stored at g^(row&7) -> 2-way max.
#define SWZ(g, r) ((((g) ^ ((r) & 7))) * 8)
__global__ __launch_bounds__(256, 3)
void gemm_presplit(const short* __restrict__ Ah, const short* __restrict__ Al,
                   const short* __restrict__ Bh, const short* __restrict__ Bl,
                   float* __restrict__ C, int M, int N, int K) {
  __shared__ short Ahs[64][64], Als[64][64];
  __shared__ short Bhs[128][64], Bls[128][64];
  const int tid = threadIdx.x;
  const int wv = tid >> 6, lane = tid & 63;
  const int wm = (wv >> 1) * 32, wn = (wv & 1) * 64;
  const int quad = lane >> 4, col = lane & 15;
  const int m0 = blockIdx.y * 64, n0 = blockIdx.x * 128;
  const int srow = tid >> 2, sg = tid & 3;

  f32x4 acc[2][4];
#pragma unroll
  for (int i = 0; i < 2; i++)
#pragma unroll
    for (int j = 0; j < 4; j++) acc[i][j] = (f32x4){0.f, 0.f, 0.f, 0.f};

  for (int k0 = 0; k0 < K; k0 += 64) {
    // stage A: 64 rows x 64 shorts (hi+lo), pure copies, swizzled
#pragma unroll
    for (int gg = 0; gg < 2; gg++) {
      int g = sg + gg * 4;
      size_t go = (size_t)(m0 + srow) * K + k0 + g * 8;
      *reinterpret_cast<short8*>(&Ahs[srow][SWZ(g, srow)]) =
          *reinterpret_cast<const short8*>(Ah + go);
      *reinterpret_cast<short8*>(&Als[srow][SWZ(g, srow)]) =
          *reinterpret_cast<const short8*>(Al + go);
    }
    // stage B: 128 rows x 64 shorts (hi+lo)
#pragma unroll
    for (int rr = 0; rr < 2; rr++) {
      int row = srow + rr * 64;
#pragma unroll
      for (int gg = 0; gg < 2; gg++) {
        int g = sg + gg * 4;
        size_t go = (size_t)(n0 + row) * K + k0 + g * 8;
        *reinterpret_cast<short8*>(&Bhs[row][SWZ(g, row)]) =
            *reinterpret_cast<const short8*>(Bh + go);
        *reinterpret_cast<short8*>(&Bls[row][SWZ(g, row)]) =
            *reinterpret_cast<const short8*>(Bl + go);
      }
    }
    __syncthreads();
#pragma unroll
    for (int ks = 0; ks < 2; ks++) {
      const int g = ks * 4 + quad;
      short8 afh[2], afl[2], bfh[4], bfl[4];
#pragma unroll
      for (int i = 0; i < 2; i++) {
        int ar = wm + i * 16 + col;
        afh[i] = *reinterpret_cast<const short8*>(&Ahs[ar][SWZ(g, ar)]);
        afl[i] = *reinterpret_cast<const short8*>(&Als[ar][SWZ(g, ar)]);
      }
#pragma unroll
      for (int j = 0; j < 4; j++) {
        int br = wn + j * 16 + col;
        bfh[j] = *reinterpret_cast<const short8*>(&Bhs[br][SWZ(g, br)]);
        bfl[j] = *reinterpret_cast<const short8*>(&Bls[br][SWZ(g, br)]);
      }
#pragma unroll
      for (int i = 0; i < 2; i++)
#pragma unroll
        for (int j = 0; j < 4; j++) {
          acc[i][j] = __builtin_amdgcn_mfma_f32_16x16x32_bf16(afh[i], bfh[j], acc[i][j], 0, 0, 0);
          acc[i][j] = __builtin_amdgcn_mfma_f32_16x16x32_bf16(afh[i], bfl[j], acc[i][j], 0, 0, 0);
          acc[i][j] = __builtin_amdgcn_mfma_f32_16x16x32_bf16(afl[i], bfh[j], acc[i][j], 0, 0, 0);
        }
    }
    __syncthreads();
  }
#pragma unroll
  for (int i = 0; i < 2; i++)
#pragma unroll
    for (int j = 0; j < 4; j++)
#pragma unroll
      for (int r = 0; r < 4; r++)
        C[(size_t)(m0 + wm + i * 16 + quad * 4 + r) * N + n0 + wn + j * 16 + col] =
            acc[i][j][r];
}

// elementwise fp32 -> bf16 hi/lo (for hs). n4 = count of float4.
__global__ __launch_bounds__(256)
void split_kernel(const float* __restrict__ in, short* __restrict__ oh,
                  short* __restrict__ ol, int n4) {
  int i = blockIdx.x * 256 + threadIdx.x;
  if (i >= n4) return;
  float4_t v = reinterpret_cast<const float4_t*>(in)[i];
  short4_t h, l;
#pragma unroll
  for (int e = 0; e < 4; e++) {
    short hh, ll;
    split2(v[e], hh, ll);
    h[e] = hh; l[e] = ll;
  }
  reinterpret_cast<short4_t*>(oh)[i] = h;
  reinterpret_cast<short4_t*>(ol)[i] = l;
}

// W fp32 [KW][NW] -> WTh/WTl bf16 rows (n_ofs+n)[KW] (transposed + split)
__global__ __launch_bounds__(256)
void wsplitT_kernel(const float* __restrict__ W, short* __restrict__ WTh,
                    short* __restrict__ WTl, int KW, int NW, int n_ofs) {
  __shared__ float T[64][65];
  const int k0 = blockIdx.x * 64, n0 = blockIdx.y * 64;
  const int tid = threadIdx.x;
  const int r = tid >> 4, c4 = (tid & 15) * 4;
#pragma unroll
  for (int p = 0; p < 4; p++) {
    float4_t v = *reinterpret_cast<const float4_t*>(
        &W[(size_t)(k0 + r + p * 16) * NW + n0 + c4]);
#pragma unroll
    for (int e = 0; e < 4; e++) T[r + p * 16][c4 + e] = v[e];
  }
  __syncthreads();
  const int n_loc = tid >> 2, kg = (tid & 3) * 16;
  short8 hv[2], lv[2];
#pragma unroll
  for (int e = 0; e < 16; e++) {
    short hh, ll;
    split2(T[kg + e][n_loc], hh, ll);
    hv[e >> 3][e & 7] = hh;
    lv[e >> 3][e & 7] = ll;
  }
  size_t base = (size_t)(n_ofs + n0 + n_loc) * KW + k0 + kg;
  *reinterpret_cast<short8*>(WTh + base) = hv[0];
  *reinterpret_cast<short8*>(WTh + base + 8) = hv[1];
  *reinterpret_cast<short8*>(WTl + base) = lv[0];
  *reinterpret_cast<short8*>(WTl + base + 8) = lv[1];
}

// ================= FALLBACK: round-7 on-the-fly GEMM (proven) =============
struct GemmSmem {
  short Ah[128][32], Al[128][32], Bh[128][32], Bl[128][32];
};
__device__ __forceinline__ void gemm_body(GemmSmem* sm, const float* __restrict__ A,
                                          const float* __restrict__ B,
                                          float* __restrict__ C, int M, int N,
                                          int K, int m0, int n0) {
  const int tid = threadIdx.x;
  const int wave = tid >> 6, lane = tid & 63;
  const int wm = (wave >> 1) * 64, wn = (wave & 1) * 64;
  const int m_in = lane & 15, kgrp = lane >> 4;
  const int bn = tid & 127;
  const int bk0 = (tid >> 7) * 16;
  f32x4 acc[4][4];
#pragma unroll
  for (int i = 0; i < 4; i++)
#pragma unroll
    for (int j = 0; j < 4; j++) acc[i][j] = (f32x4){0.f, 0.f, 0.f, 0.f};
  for (int k0 = 0; k0 < K; k0 += 32) {
#pragma unroll
    for (int i = 0; i < 4; i++) {
      int f = tid + i * 256;
      int m = f >> 3, c4 = (f & 7) << 2;
      float4_t av = *reinterpret_cast<const float4_t*>(
          &A[(size_t)(m0 + m) * K + (k0 + c4)]);
      short4_t hv, lv;
#pragma unroll
      for (int e = 0; e < 4; e++) {
        short h, l;
        split2(av[e], h, l);
        hv[e] = h; lv[e] = l;
      }
      *reinterpret_cast<short4_t*>(&sm->Ah[m][c4]) = hv;
      *reinterpret_cast<short4_t*>(&sm->Al[m][c4]) = lv;
    }
    {
      const float* bp = &B[(size_t)(k0 + bk0) * N + (n0 + bn)];
      float vals[16];
#pragma unroll
      for (int kk = 0; kk < 16; kk++) vals[kk] = bp[(size_t)kk * N];
#pragma unroll
      for (int c = 0; c < 4; c++) {
        short4_t hv, lv;
#pragma unroll
        for (int e = 0; e < 4; e++) {
          short h, l;
          split2(vals[c * 4 + e], h, l);
          hv[e] = h; lv[e] = l;
        }
        *reinterpret_cast<short4_t*>(&sm->Bh[bn][bk0 + c * 4]) = hv;
        *reinterpret_cast<short4_t*>(&sm->Bl[bn][bk0 + c * 4]) = lv;
      }
    }
    __syncthreads();
    short8 ah[4], al[4], bh[4], bl[4];
#pragma unroll
    for (int i = 0; i < 4; i++) {
      ah[i] = *reinterpret_cast<const short8*>(&sm->Ah[wm + i * 16 + m_in][kgrp * 8]);
      al[i] = *reinterpret_cast<const short8*>(&sm->Al[wm + i * 16 + m_in][kgrp * 8]);
    }
#pragma unroll
    for (int j = 0; j < 4; j++) {
      bh[j] = *reinterpret_cast<const short8*>(&sm->Bh[wn + j * 16 + m_in][kgrp * 8]);
      bl[j] = *reinterpret_cast<const short8*>(&sm->Bl[wn + j * 16 + m_in][kgrp * 8]);
    }
#pragma unroll
    for (int i = 0; i < 4; i++)
#pragma unroll
      for (int j = 0; j < 4; j++) {
        acc[i][j] = __builtin_amdgcn_mfma_f32_16x16x32_bf16(ah[i], bh[j], acc[i][j], 0, 0, 0);
        acc[i][j] = __builtin_amdgcn_mfma_f32_16x16x32_bf16(ah[i], bl[j], acc[i][j], 0, 0, 0);
        acc[i][j] = __builtin_amdgcn_mfma_f32_16x16x32_bf16(al[i], bh[j], acc[i][j], 0, 0, 0);
      }
    __syncthreads();
  }
#pragma unroll
  for (int i = 0; i < 4; i++)
#pragma unroll
    for (int j = 0; j < 4; j++)
#pragma unroll
      for (int r = 0; r < 4; r++)
        C[(size_t)(m0 + wm + i * 16 + kgrp * 4 + r) * N + n0 + wn + j * 16 + m_in] =
            acc[i][j][r];
}
__global__ __launch_bounds__(256)
void gemm_mfma(const float* __restrict__ A, const float* __restrict__ B,
               float* __restrict__ C, int M, int N, int K) {
  __shared__ GemmSmem sm;
  gemm_body(&sm, A, B, C, M, N, K, blockIdx.y * 128, blockIdx.x * 128);
}
__global__ __launch_bounds__(256)
void gemm_mfma_kv(const float* __restrict__ A, const float* __restrict__ B0,
                  const float* __restrict__ B1, float* __restrict__ C0,
                  float* __restrict__ C1, int M, int N, int K) {
  __shared__ GemmSmem sm;
  const int nb = N / 128;
  const int half = blockIdx.x >= nb;
  gemm_body(&sm, A, half ? B1 : B0, half ? C1 : C0, M, N, K,
            blockIdx.y * 128, (blockIdx.x - half * nb) * 128);
}

// ================= norms (stride-parametrized) =================
__global__ __launch_bounds__(256)
void qnorm_kernel(float* __restrict__ io, int rs, const float* __restrict__ w,
                  const float* __restrict__ cosb, const float* __restrict__ sinb) {
  const int sq = blockIdx.x / NH;
  const int h = blockIdx.x % NH;
  const int d = threadIdx.x;
  const size_t idx = (size_t)sq * rs + h * HD + d;
  float x = io[idx];
  float v = x * x;
#pragma unroll
  for (int off = 32; off; off >>= 1) v += __shfl_down(v, off);
  __shared__ float red[4];
  __shared__ float sscale;
  __shared__ float nb[HD];
  if ((d & 63) == 0) red[d >> 6] = v;
  __syncthreads();
  if (d == 0)
    sscale = rsqrtf((red[0] + red[1] + red[2] + red[3]) * (1.0f / HD) + 1e-6f);
  __syncthreads();
  float n = x * sscale * w[d];
  nb[d] = n;
  __syncthreads();
  float other = (d < HD / 2) ? -nb[d + HD / 2] : nb[d - HD / 2];
  io[idx] = n * cosb[(size_t)sq * HD + d] + other * sinb[(size_t)sq * HD + d];
}

__global__ __launch_bounds__(256)
void knorm_split_kernel(const float* __restrict__ in, int rs,
                        short* __restrict__ kh, short* __restrict__ kl,
                        const float* __restrict__ w, const float* __restrict__ cosb,
                        const float* __restrict__ sinb) {
  const int sq = blockIdx.x / NKV;
  const int h = blockIdx.x % NKV;
  const int d = threadIdx.x;
  float x = in[(size_t)sq * rs + h * HD + d];
  float v = x * x;
#pragma unroll
  for (int off = 32; off; off >>= 1) v += __shfl_down(v, off);
  __shared__ float red[4];
  __shared__ float sscale;
  __shared__ float nb[HD];
  if ((d & 63) == 0) red[d >> 6] = v;
  __syncthreads();
  if (d == 0)
    sscale = rsqrtf((red[0] + red[1] + red[2] + red[3]) * (1.0f / HD) + 1e-6f);
  __syncthreads();
  float n = x * sscale * w[d];
  nb[d] = n;
  __syncthreads();
  float other = (d < HD / 2) ? -nb[d + HD / 2] : nb[d - HD / 2];
  n = n * cosb[(size_t)sq * HD + d] + other * sinb[(size_t)sq * HD + d];
  short hh, ll;
  split2(n, hh, ll);
  kh[((size_t)sq * NKV + h) * HD + d] = hh;
  kl[((size_t)sq * NKV + h) * HD + d] = ll;
}

__global__ __launch_bounds__(256)
void vnormT_kernel(const float* __restrict__ in, int rs, short* __restrict__ vtb) {
  const int sq = blockIdx.x / NKV;
  const int h = blockIdx.x % NKV;
  const int d = threadIdx.x;
  float x = in[(size_t)sq * rs + h * HD + d];
  float v = x * x;
#pragma unroll
  for (int off = 32; off; off >>= 1) v += __shfl_down(v, off);
  __shared__ float red[4];
  __shared__ float sscale;
  if ((d & 63) == 0) red[d >> 6] = v;
  __syncthreads();
  if (d == 0)
    sscale = rsqrtf((red[0] + red[1] + red[2] + red[3]) * (1.0f / HD) + 1e-6f);
  __syncthreads();
  vtb[((size_t)h * HD + d) * S_LEN + sq] = bf16_rne(x * sscale);
}

// ================= flash attention (round-7 proven, + q row stride) ========
__global__ __launch_bounds__(256, 2)
void flash_attn2(const float* __restrict__ qn, int qrs,
                 const short* __restrict__ kh, const short* __restrict__ kl,
                 const short* __restrict__ vtb, float* __restrict__ oA,
                 float* __restrict__ oB, float* __restrict__ mlA,
                 float* __restrict__ mlB) {
  __shared__ short Kh[32][264], Kl[32][264];
  __shared__ short Vb[256][40];
  __shared__ short Ps[64][40];
  const int qt = blockIdx.x, h = blockIdx.y, sp = blockIdx.z;
  const int kvh = h >> 1;
  const int q0 = qt * 64;
  const int tid = threadIdx.x;
  const int w = tid >> 6, lane = tid & 63;
  const int quad = lane >> 4, col = lane & 15;
  float* oOut = sp ? oB : oA;
  float* mlOut = sp ? mlB : mlA;
  short8 qh[8], ql[8];
  {
    const float* qrow = qn + (size_t)(q0 + w * 16 + col) * qrs + h * HD;
#pragma unroll
    for (int s8 = 0; s8 < 8; s8++) {
      int d0 = s8 * 32 + quad * 8;
      float4_t a = *reinterpret_cast<const float4_t*>(qrow + d0);
      float4_t b = *reinterpret_cast<const float4_t*>(qrow + d0 + 4);
#pragma unroll
      for (int e = 0; e < 4; e++) {
        short hh, ll;
        split2(a[e], hh, ll);
        qh[s8][e] = hh; ql[s8][e] = ll;
        split2(b[e], hh, ll);
        qh[s8][4 + e] = hh; ql[s8][4 + e] = ll;
      }
    }
  }
  f32x4 o[16];
#pragma unroll
  for (int i = 0; i < 16; i++) o[i] = (f32x4){0.f, 0.f, 0.f, 0.f};
  float m_r[4] = {-INFINITY, -INFINITY, -INFINITY, -INFINITY};
  float l_r[4] = {0.f, 0.f, 0.f, 0.f};
  const int lo_t = (q0 > 1023) ? ((q0 - 1023) >> 5) : 0;
  const int hi_t = (q0 + 63) >> 5;
  const int halfn = (hi_t - lo_t + 2) >> 1;
  const int t0 = sp ? (lo_t + halfn) : lo_t;
  const int t1 = sp ? hi_t : (lo_t + halfn - 1);
  for (int kt = t0; kt <= t1; kt++) {
    const int kt0 = kt << 5;
    __syncthreads();
#pragma unroll
    for (int i = 0; i < 4; i++) {
      int idx = tid + i * 256;
      int row = idx >> 5, g = idx & 31;
      size_t gofs = ((size_t)(kt0 + row) * NKV + kvh) * HD + g * 8;
      *reinterpret_cast<short8*>(&Kh[row][g * 8]) =
          *reinterpret_cast<const short8*>(kh + gofs);
      *reinterpret_cast<short8*>(&Kl[row][g * 8]) =
          *reinterpret_cast<const short8*>(kl + gofs);
    }
#pragma unroll
    for (int i = 0; i < 4; i++) {
      int idx = tid + i * 256;
      int d = idx >> 2, g = idx & 3;
      *reinterpret_cast<short8*>(&Vb[d][g * 8]) = *reinterpret_cast<const short8*>(
          vtb + ((size_t)kvh * HD + d) * S_LEN + kt0 + g * 8);
    }
    __syncthreads();
    f32x4 sc[2];
    sc[0] = (f32x4){0.f, 0.f, 0.f, 0.f};
    sc[1] = (f32x4){0.f, 0.f, 0.f, 0.f};
#pragma unroll
    for (int s8 = 0; s8 < 8; s8++) {
#pragma unroll
      for (int nt = 0; nt < 2; nt++) {
        const short8 bh = *reinterpret_cast<const short8*>(
            &Kh[nt * 16 + col][s8 * 32 + quad * 8]);
        const short8 bl = *reinterpret_cast<const short8*>(
            &Kl[nt * 16 + col][s8 * 32 + quad * 8]);
        sc[nt] = __builtin_amdgcn_mfma_f32_16x16x32_bf16(qh[s8], bh, sc[nt], 0, 0, 0);
        sc[nt] = __builtin_amdgcn_mfma_f32_16x16x32_bf16(qh[s8], bl, sc[nt], 0, 0, 0);
        sc[nt] = __builtin_amdgcn_mfma_f32_16x16x32_bf16(ql[s8], bh, sc[nt], 0, 0, 0);
      }
    }
#pragma unroll
    for (int r = 0; r < 4; r++) {
      const int q_abs = q0 + w * 16 + quad * 4 + r;
#pragma unroll
      for (int nt = 0; nt < 2; nt++) {
        int k_abs = kt0 + nt * 16 + col;
        bool valid = (k_abs <= q_abs) && (q_abs - k_abs < WINDOW);
        if (!valid) sc[nt][r] = -INFINITY;
      }
      float mx = fmaxf(sc[0][r], sc[1][r]);
      mx = fmaxf(mx, __shfl_xor(mx, 1));
      mx = fmaxf(mx, __shfl_xor(mx, 2));
      mx = fmaxf(mx, __shfl_xor(mx, 4));
      mx = fmaxf(mx, __shfl_xor(mx, 8));
      float mn = fmaxf(m_r[r], mx);
      float alpha = (mn == -INFINITY) ? 1.f : __expf(m_r[r] - mn);
      m_r[r] = mn;
      float rsum = 0.f;
#pragma unroll
      for (int nt = 0; nt < 2; nt++) {
        float s = sc[nt][r];
        float e = (s == -INFINITY) ? 0.f : __expf(s - mn);
        rsum += e;
        Ps[w * 16 + quad * 4 + r][nt * 16 + col] = bf16_rne(e);
      }
      rsum += __shfl_xor(rsum, 1);
      rsum += __shfl_xor(rsum, 2);
      rsum += __shfl_xor(rsum, 4);
      rsum += __shfl_xor(rsum, 8);
      l_r[r] = l_r[r] * alpha + rsum;
#pragma unroll
      for (int nt2 = 0; nt2 < 16; nt2++) o[nt2][r] *= alpha;
    }
    __syncthreads();
    {
      const short8 pa = *reinterpret_cast<const short8*>(&Ps[w * 16 + col][quad * 8]);
#pragma unroll
      for (int nt = 0; nt < 16; nt++) {
        const short8 vb = *reinterpret_cast<const short8*>(&Vb[nt * 16 + col][quad * 8]);
        o[nt] = __builtin_amdgcn_mfma_f32_16x16x32_bf16(pa, vb, o[nt], 0, 0, 0);
      }
    }
  }
#pragma unroll
  for (int r = 0; r < 4; r++) {
    const int row = q0 + w * 16 + quad * 4 + r;
    const size_t base = ((size_t)row * NH + h) * HD;
#pragma unroll
    for (int nt = 0; nt < 16; nt++) oOut[base + nt * 16 + col] = o[nt][r];
    if (col == 0) {
      mlOut[((size_t)row * NH + h) * 2] = m_r[r];
      mlOut[((size_t)row * NH + h) * 2 + 1] = l_r[r];
    }
  }
}

// combine splits; mode 0 -> fp32 ctx, mode 1 -> split bf16 ctxh/ctxl
__global__ __launch_bounds__(256)
void combine_kernel(const float* __restrict__ oA, const float* __restrict__ oB,
                    const float* __restrict__ mlA, const float* __restrict__ mlB,
                    float* __restrict__ ctxf, short* __restrict__ ctxh,
                    short* __restrict__ ctxl, int mode) {
  const int idx = blockIdx.x;
  const int d = threadIdx.x;
  const float mA = mlA[(size_t)idx * 2], lA = mlA[(size_t)idx * 2 + 1];
  const float mB = mlB[(size_t)idx * 2], lB = mlB[(size_t)idx * 2 + 1];
  const float m = fmaxf(mA, mB);
  const float eA = (mA == -INFINITY) ? 0.f : __expf(mA - m);
  const float eB = (mB == -INFINITY) ? 0.f : __expf(mB - m);
  const float inv = 1.0f / (eA * lA + eB * lB);
  const size_t b = (size_t)idx * HD + d;
  float v = (eA * oA[b] + eB * oB[b]) * inv;
  if (mode == 0) {
    ctxf[b] = v;
  } else {
    short hh, ll;
    split2(v, hh, ll);
    ctxh[b] = hh;
    ctxl[b] = ll;
  }
}

extern "C" void kernel_launch(void* const* d_in, const int* in_sizes, int n_in,
                              void* d_out, int out_size, void* d_ws, size_t ws_size,
                              hipStream_t stream) {
  const float* hs   = (const float*)d_in[0];
  const float* cosb = (const float*)d_in[1];
  const float* sinb = (const float*)d_in[2];
  const float* wq   = (const float*)d_in[3];
  const float* wk   = (const float*)d_in[4];
  const float* wv   = (const float*)d_in[5];
  const float* wo   = (const float*)d_in[6];
  const float* qw   = (const float*)d_in[7];
  const float* kw   = (const float*)d_in[8];
  dim3 blk(256);

  // ---- Plan A sizes (bytes) ----
  const size_t szAh   = (size_t)S_LEN * HID * 2;          // 10.49 MB
  const size_t szQKVT = (size_t)4096 * HID * 2;           // 20.97 MB
  const size_t szWoT  = (size_t)HID * 2048 * 2;           // 10.49 MB
  const size_t szCqkv = (size_t)S_LEN * 4096 * 4;         // 33.55 MB
  const size_t szKh   = (size_t)S_LEN * NKV * HD * 2;     // 4.19 MB
  const size_t szMl   = (size_t)S_LEN * NH * 2 * 4;       // 131 KB
  const size_t NEED = 256 + 2 * szAh + 2 * szQKVT + 2 * szWoT + szCqkv +
                      3 * szKh + 2 * szMl + 4096;

  if (ws_size >= NEED) {
    // ================= PLAN A =================
    char* p = (char*)d_ws + 256;
    short* Ah     = (short*)p;              p += szAh;   // later: oA (fp32, 16.8MB <= 21MB)
    short* Al     = (short*)p;              p += szAh;
    short* qkvTh  = (short*)p;              p += szQKVT; // later: ctxh/ctxl (16.8 <= 41.9)
    short* qkvTl  = (short*)p;              p += szQKVT;
    short* woTh   = (short*)p;              p += szWoT;
    short* woTl   = (short*)p;              p += szWoT;
    float* Cqkv   = (float*)p;              p += szCqkv;
    short* kh     = (short*)p;              p += szKh;
    short* kl     = (short*)p;              p += szKh;
    short* vtb    = (short*)p;              p += szKh;
    float* mlA    = (float*)p;              p += szMl;
    float* mlB    = (float*)p;              p += szMl;
    float* oA     = (float*)Ah;             // alias (Ah+Al dead after qkv GEMM)
    float* oB     = (float*)d_out;          // dead until out-proj
    short* ctxh   = qkvTh;                  // alias (qkvT dead after qkv GEMM)
    short* ctxl   = qkvTh + (size_t)S_LEN * NH * HD;

    // prep: split hs; split+transpose weights (wq|wk|wv fused rows, wo)
    split_kernel<<<(S_LEN * HID / 4 + 255) / 256, blk, 0, stream>>>(
        hs, Ah, Al, S_LEN * HID / 4);
    wsplitT_kernel<<<dim3(HID / 64, 2048 / 64), blk, 0, stream>>>(
        wq, qkvTh, qkvTl, HID, 2048, 0);
    wsplitT_kernel<<<dim3(HID / 64, 1024 / 64), blk, 0, stream>>>(
        wk, qkvTh, qkvTl, HID, 1024, 2048);
    wsplitT_kernel<<<dim3(HID / 64, 1024 / 64), blk, 0, stream>>>(
        wv, qkvTh, qkvTl, HID, 1024, 3072);
    wsplitT_kernel<<<dim3(2048 / 64, HID / 64), blk, 0, stream>>>(
        wo, woTh, woTl, 2048, HID, 0);
    // fused q|k|v projection: [2048][4096] = A[2048][2560] x B[4096][2560]^T
    gemm_presplit<<<dim3(4096 / 128, S_LEN / 64), blk, 0, stream>>>(
        Ah, Al, qkvTh, qkvTl, Cqkv, S_LEN, 4096, HID);
    // norms (q in place inside Cqkv; k/v from their column slices)
    qnorm_kernel<<<S_LEN * NH, blk, 0, stream>>>(Cqkv, 4096, qw, cosb, sinb);
    knorm_split_kernel<<<S_LEN * NKV, blk, 0, stream>>>(Cqkv + 2048, 4096, kh, kl,
                                                        kw, cosb, sinb);
    vnormT_kernel<<<S_LEN * NKV, blk, 0, stream>>>(Cqkv + 3072, 4096, vtb);
    // flash attention (split-k x2)
    flash_attn2<<<dim3(S_LEN / 64, NH, 2), blk, 0, stream>>>(
        Cqkv, 4096, kh, kl, vtb, oA, oB, mlA, mlB);
    combine_kernel<<<S_LEN * NH, blk, 0, stream>>>(oA, oB, mlA, mlB, nullptr,
                                                   ctxh, ctxl, 1);
    // out projection: [2048][2560] = ctx[2048][2048] x woT[2560][2048]^T
    gemm_presplit<<<dim3(HID / 128, S_LEN / 64), blk, 0, stream>>>(
        ctxh, ctxl, woTh, woTl, (float*)d_out, S_LEN, HID, 2048);
  } else {
    // ================= FALLBACK (round-7 pipeline, 44.5 MB) =================
    float* qc  = (float*)((char*)d_ws + 256);
    float* Xk  = qc + (size_t)S_LEN * NH * HD;
    float* Xv  = Xk + (size_t)S_LEN * NKV * HD;
    float* oA  = Xk;
    short* kh  = (short*)(Xv + (size_t)S_LEN * NKV * HD);
    short* kl  = kh + (size_t)S_LEN * NKV * HD;
    short* vtb = kl + (size_t)S_LEN * NKV * HD;
    float* mlA = (float*)(vtb + (size_t)S_LEN * NKV * HD);
    float* mlB = mlA + (size_t)S_LEN * NH * 2;
    float* oB  = (float*)d_out;
    gemm_mfma_kv<<<dim3(16, S_LEN / 128), blk, 0, stream>>>(
        hs, wk, wv, Xk, Xv, S_LEN, NKV * HD, HID);
    knorm_split_kernel<<<S_LEN * NKV, blk, 0, stream>>>(Xk, NKV * HD, kh, kl,
                                                        kw, cosb, sinb);
    vnormT_kernel<<<S_LEN * NKV, blk, 0, stream>>>(Xv, NKV * HD, vtb);
    gemm_mfma<<<dim3((NH * HD) / 128, S_LEN / 128), blk, 0, stream>>>(
        hs, wq, qc, S_LEN, NH * HD, HID);
    qnorm_kernel<<<S_LEN * NH, blk, 0, stream>>>(qc, NH * HD, qw, cosb, sinb);
    flash_attn2<<<dim3(S_LEN / 64, NH, 2), blk, 0, stream>>>(
        qc, NH * HD, kh, kl, vtb, oA, oB, mlA, mlB);
    combine_kernel<<<S_LEN * NH, blk, 0, stream>>>(oA, oB, mlA, mlB, qc,
                                                   nullptr, nullptr, 0);
    gemm_mfma<<<dim3(HID / 128, S_LEN / 128), blk, 0, stream>>>(
        qc, wo, (float*)d_out, S_LEN, HID, NH * HD);
  }
}